// Round 2
// baseline (2408.125 us; speedup 1.0000x reference)
//
#include <hip/hip_runtime.h>
#include <hip/hip_bf16.h>

// SegFormer block, VALU baseline. FP32 inputs/outputs (per reference dtypes);
// bf16 intermediates for bandwidth, fp32 residual stream for precision.
// Workspace layout (requires ws_size >= 117,964,800 bytes):
//   [0,               33554432)  x2   fp32 (B,N,C)   post-attention residual
//   [33554432,        50331648)  h    bf16 (B,N,C)   LN1 output
//   [50331648,        50593792)  k    bf16 (B,Nr,C)
//   [50593792,        50855936)  v    bf16 (B,Nr,C)
//   [50855936,       117964800)  f    bf16 (B,N,HID) fc1 output

typedef __hip_bfloat16 bf16;
typedef __hip_bfloat162 bf162;

#define N_TOK 16384
#define CDIM 64
#define NR 256
#define HID 256
#define EPS 1e-5f
#define SROW 258   // LDS row stride for kT/vT: 129 words === 1 mod 32 -> conflict-free

__device__ __forceinline__ float b2f(bf16 v) { return __bfloat162float(v); }
__device__ __forceinline__ bf16 f2b(float v) { return __float2bfloat16(v); }

__device__ __forceinline__ float wred_sum(float v) {
#pragma unroll
  for (int o = 32; o >= 1; o >>= 1) v += __shfl_xor(v, o);
  return v;
}
__device__ __forceinline__ float wred_max(float v) {
#pragma unroll
  for (int o = 32; o >= 1; o >>= 1) v = fmaxf(v, __shfl_xor(v, o));
  return v;
}

// ---------------- kernel 1: h = LN1(x) ----------------
__global__ __launch_bounds__(256) void k_ln1(
    const float* __restrict__ x, const float* __restrict__ g, const float* __restrict__ bb,
    bf16* __restrict__ h) {
  const int gid = blockIdx.x * 256 + threadIdx.x;
  const int lane = gid & 63;
  const size_t base = ((size_t)(gid >> 6)) << 6;
  const float xv = x[base + lane];
  const float mean = wred_sum(xv) * (1.f / 64.f);
  const float d = xv - mean;
  const float var = wred_sum(d * d) * (1.f / 64.f);
  h[base + lane] = f2b(d * rsqrtf(var + EPS) * g[lane] + bb[lane]);
}

// ---------------- kernel 2: 8x8/s8 conv + srnLN + kv projection ----------------
// 512 blocks x 256 thr; block = 4 patches (one per wave), b = blockIdx/64.
__global__ __launch_bounds__(256) void k_srconv(
    const bf16* __restrict__ h, const float* __restrict__ srw, const float* __restrict__ srb,
    const float* __restrict__ sng, const float* __restrict__ snb,
    const float* __restrict__ kvw, const float* __restrict__ kvb,
    bf16* __restrict__ kbuf, bf16* __restrict__ vbuf) {
  __shared__ bf16 pat[4][4096];
  const int tid = threadIdx.x;
  const int b = blockIdx.x >> 6;
  const int nr0 = (blockIdx.x & 63) << 2;
  for (int i = tid; i < 4 * 4096; i += 256) {
    const int pp = i >> 12, idx = i & 4095;
    const int sp = idx >> 6, ci = idx & 63;
    const int nr = nr0 + pp;
    const int py = nr >> 4, px = nr & 15;
    const int n = ((py << 3) + (sp >> 3)) * 128 + (px << 3) + (sp & 7);
    pat[pp][idx] = h[(((size_t)b * N_TOK) + n) * CDIM + ci];
  }
  __syncthreads();
  const int p = tid >> 6, co = tid & 63;
  float acc = srb[co];
#pragma unroll 8
  for (int k = 0; k < 4096; k++) {
    acc += b2f(pat[p][k]) * srw[k * 64 + co];
  }
  // srn layernorm across the wave (lane == channel)
  const float mean = wred_sum(acc) * (1.f / 64.f);
  const float d = acc - mean;
  const float var = wred_sum(d * d) * (1.f / 64.f);
  const float xn = d * rsqrtf(var + EPS) * sng[co] + snb[co];
  // kv projection: k = cols [0,64), v = cols [64,128)
  float ka = kvb[co];
  float va = kvb[64 + co];
#pragma unroll
  for (int ci = 0; ci < 64; ci++) {
    const float xv = __shfl(xn, ci);
    ka += xv * kvw[ci * 128 + co];
    va += xv * kvw[ci * 128 + 64 + co];
  }
  const int nr = nr0 + p;
  kbuf[(((size_t)b * NR) + nr) * CDIM + co] = f2b(ka);
  vbuf[(((size_t)b * NR) + nr) * CDIM + co] = f2b(va);
}

// ---------------- kernel 3: q proj + attention + out proj + residual ----------------
// 512 blocks x 256 thr; block = 256 queries of one batch; wave = 64 sequential queries.
// Lane m-partition for scores: lane l holds m in {2l, 2l+1, 128+2l, 129+2l}.
__global__ __launch_bounds__(256) void k_attn(
    const bf16* __restrict__ h, const float* __restrict__ x,
    const float* __restrict__ qw, const float* __restrict__ qb,
    const bf16* __restrict__ kbuf, const bf16* __restrict__ vbuf,
    const float* __restrict__ pw, const float* __restrict__ pb,
    float* __restrict__ x2) {
  __shared__ bf16 kT[64 * SROW];  // kT[c][m] = k[m][c]
  __shared__ bf16 vT[64 * SROW];  // vT[c][m] = v[m][c]
  const int tid = threadIdx.x, lane = tid & 63, wv = tid >> 6;
  const int b = blockIdx.x >> 6;
  const int q0 = (blockIdx.x & 63) << 8;

  for (int i = tid; i < NR * CDIM; i += 256) {
    const int m = i >> 6, c = i & 63;
    kT[c * SROW + m] = kbuf[(((size_t)b * NR) + m) * CDIM + c];
    vT[c * SROW + m] = vbuf[(((size_t)b * NR) + m) * CDIM + c];
  }
  // register-resident weight columns (column = lane)
  float wqr[64], wpr[64];
#pragma unroll
  for (int j = 0; j < 64; j++) wqr[j] = qw[j * 64 + lane];
#pragma unroll
  for (int c = 0; c < 64; c++) wpr[c] = pw[c * 64 + lane];
  const float qbias = qb[lane];
  const float pbias = pb[lane];
  __syncthreads();

  for (int qi = 0; qi < 64; qi++) {
    const int row = q0 + (wv << 6) + qi;
    const size_t base = (((size_t)b * N_TOK) + row) * CDIM;
    const float hv = b2f(h[base + lane]);
    // q = (h @ q_w + q_b) * scale   (lane = output channel)
    float qv = qbias;
#pragma unroll
    for (int j = 0; j < 64; j++) qv += __shfl(hv, j) * wqr[j];
    qv *= 0.125f;

    // scores
    float s0 = 0.f, s1 = 0.f, s2 = 0.f, s3 = 0.f;
#pragma unroll
    for (int c = 0; c < 64; c++) {
      const float qc = __shfl(qv, c);
      const float2 a = __bfloat1622float2(*(const bf162*)(&kT[c * SROW + 2 * lane]));
      const float2 bb = __bfloat1622float2(*(const bf162*)(&kT[c * SROW + 128 + 2 * lane]));
      s0 += qc * a.x; s1 += qc * a.y; s2 += qc * bb.x; s3 += qc * bb.y;
    }
    // softmax (unnormalized; fold 1/sum into output)
    const float mx = wred_max(fmaxf(fmaxf(s0, s1), fmaxf(s2, s3)));
    const float e0 = __expf(s0 - mx), e1 = __expf(s1 - mx);
    const float e2 = __expf(s2 - mx), e3 = __expf(s3 - mx);
    const float rsum = 1.0f / wred_sum(e0 + e1 + e2 + e3);

    // o[c] = sum_m p[m] * v[m][c]   (lane = channel now; p via shfl)
    float o = 0.f;
#pragma unroll
    for (int mm = 0; mm < 64; mm++) {
      const float p0 = __shfl(e0, mm);
      const float p1 = __shfl(e1, mm);
      const float p2 = __shfl(e2, mm);
      const float p3 = __shfl(e3, mm);
      const float2 a = __bfloat1622float2(*(const bf162*)(&vT[lane * SROW + 2 * mm]));
      const float2 bb = __bfloat1622float2(*(const bf162*)(&vT[lane * SROW + 128 + 2 * mm]));
      o += p0 * a.x + p1 * a.y + p2 * bb.x + p3 * bb.y;
    }
    o *= rsum;

    // out proj + residual
    float pa = pbias;
#pragma unroll
    for (int c = 0; c < 64; c++) pa += __shfl(o, c) * wpr[c];
    x2[base + lane] = x[base + lane] + pa;
  }
}

// ---------------- kernel 4: LN2 + fc1 ----------------
// 1024 blocks x 256 thr; thread = output column, 128 rows/block.
__global__ __launch_bounds__(256) void k_fc1(
    const float* __restrict__ x2, const float* __restrict__ g, const float* __restrict__ bb,
    const float* __restrict__ w1, const float* __restrict__ b1,
    bf16* __restrict__ f) {
  const int tid = threadIdx.x, lane = tid & 63;
  float wr[64];
#pragma unroll
  for (int c = 0; c < 64; c++) wr[c] = w1[c * HID + tid];
  const float bias = b1[tid];
  const float gl = g[lane], bl = bb[lane];
  const int r0 = blockIdx.x << 7;
  for (int r = 0; r < 128; r++) {
    const size_t base = ((size_t)(r0 + r)) << 6;
    const float xv = x2[base + lane];
    const float mean = wred_sum(xv) * (1.f / 64.f);
    const float d = xv - mean;
    const float var = wred_sum(d * d) * (1.f / 64.f);
    const float hn = d * rsqrtf(var + EPS) * gl + bl;
    float acc = bias;
#pragma unroll
    for (int c = 0; c < 64; c++) acc += __shfl(hn, c) * wr[c];
    f[((size_t)(r0 + r)) * HID + tid] = f2b(acc);
  }
}

// ---------------- kernel 5: dw 3x3 + gelu(exact) + fc2 + residual ----------------
// 1024 blocks x 256 thr; thread = hid channel for dw/gelu, then 4-way K-split fc2.
__global__ __launch_bounds__(256) void k_out(
    const bf16* __restrict__ f, const float* __restrict__ dww,
    const float* __restrict__ x2,
    const float* __restrict__ w2, const float* __restrict__ fc2b,
    float* __restrict__ out) {
  __shared__ float gels[256];
  __shared__ float parts[4][64];
  const int tid = threadIdx.x, lane = tid & 63, wv = tid >> 6;
  float dwr[9];
#pragma unroll
  for (int i = 0; i < 9; i++) dwr[i] = dww[i * HID + tid];
  float wr[64];
#pragma unroll
  for (int c = 0; c < 64; c++) wr[c] = w2[(wv * 64 + c) * CDIM + lane];
  const float bias = fc2b[lane];
  const int r0 = blockIdx.x << 7;
  for (int r = 0; r < 128; r++) {
    const int row = r0 + r;
    const int bb = row >> 14;
    const int n = row & 16383;
    const int y = n >> 7, xw = n & 127;
    float acc = 0.f;
#pragma unroll
    for (int dy = 0; dy < 3; dy++) {
      const int yy = y + dy - 1;
      if (yy < 0 || yy > 127) continue;
#pragma unroll
      for (int dx = 0; dx < 3; dx++) {
        const int xx = xw + dx - 1;
        if (xx < 0 || xx > 127) continue;
        acc += b2f(f[((((size_t)bb << 14) + (yy << 7) + xx) << 8) + tid]) * dwr[dy * 3 + dx];
      }
    }
    const float ge = 0.5f * acc * (1.f + erff(acc * 0.70710678118654752f));
    gels[tid] = ge;
    __syncthreads();
    float oa = 0.f;
#pragma unroll
    for (int c = 0; c < 64; c++) oa += gels[(wv << 6) + c] * wr[c];
    parts[wv][lane] = oa;
    __syncthreads();
    if (wv == 0) {
      const float t = parts[0][lane] + parts[1][lane] + parts[2][lane] + parts[3][lane]
                      + bias + x2[((size_t)row << 6) + lane];
      out[((size_t)row << 6) + lane] = t;
    }
    __syncthreads();
  }
}

extern "C" void kernel_launch(void* const* d_in, const int* in_sizes, int n_in,
                              void* d_out, int out_size, void* d_ws, size_t ws_size,
                              hipStream_t stream) {
  const float* x    = (const float*)d_in[0];
  // d_in[1]=H, d_in[2]=W (ints, fixed 128)
  const float* ln1g = (const float*)d_in[3];
  const float* ln1b = (const float*)d_in[4];
  const float* qw   = (const float*)d_in[5];
  const float* qb   = (const float*)d_in[6];
  const float* kvw  = (const float*)d_in[7];
  const float* kvb  = (const float*)d_in[8];
  const float* pw   = (const float*)d_in[9];
  const float* pb   = (const float*)d_in[10];
  const float* srw  = (const float*)d_in[11];
  const float* srb  = (const float*)d_in[12];
  const float* sng  = (const float*)d_in[13];
  const float* snb  = (const float*)d_in[14];
  const float* ln2g = (const float*)d_in[15];
  const float* ln2b = (const float*)d_in[16];
  const float* w1   = (const float*)d_in[17];
  const float* b1   = (const float*)d_in[18];
  const float* dww  = (const float*)d_in[19];
  const float* w2   = (const float*)d_in[20];
  const float* b2v  = (const float*)d_in[21];
  float* out = (float*)d_out;

  char* ws = (char*)d_ws;
  float* x2   = (float*)ws;                   // 33,554,432 B
  bf16*  h    = (bf16*)(ws + 33554432);       // 16,777,216 B
  bf16*  kbuf = (bf16*)(ws + 50331648);       //    262,144 B
  bf16*  vbuf = (bf16*)(ws + 50593792);       //    262,144 B
  bf16*  fbuf = (bf16*)(ws + 50855936);       // 67,108,864 B

  k_ln1   <<<32768, 256, 0, stream>>>(x, ln1g, ln1b, h);
  k_srconv<<<  512, 256, 0, stream>>>(h, srw, srb, sng, snb, kvw, kvb, kbuf, vbuf);
  k_attn  <<<  512, 256, 0, stream>>>(h, x, qw, qb, kbuf, vbuf, pw, pb, x2);
  k_fc1   <<< 1024, 256, 0, stream>>>(x2, ln2g, ln2b, w1, b1, fbuf);
  k_out   <<< 1024, 256, 0, stream>>>(fbuf, dww, x2, w2, b2v, out);
}

// Round 3
// 1146.758 us; speedup vs baseline: 2.0999x; 2.0999x over previous
//
#include <hip/hip_runtime.h>
#include <hip/hip_bf16.h>

// SegFormer block. R2: MFMA flash attention (16x16x32 bf16), rest unchanged.
// Workspace layout (requires ws_size >= 117,964,800 bytes):
//   [0,               33554432)  x2    fp32 (B,N,C)   post-attention residual
//   [33554432,        50331648)  h     bf16 (B,N,C)   LN1 output
//   [50331648,        50593792)  k     bf16 (B,Nr,C)  natural (key, ch)
//   [50593792,        50855936)  vT    bf16 (B,C,Nr)  transposed (ch, key)
//   [50855936,       117964800)  f     bf16 (B,N,HID) fc1 output

typedef __hip_bfloat16 bf16;
typedef __hip_bfloat162 bf162;
typedef __attribute__((ext_vector_type(8))) short s8v;   // 8 bf16 (4 VGPRs)
typedef __attribute__((ext_vector_type(4))) float f4v;   // MFMA C/D

#define N_TOK 16384
#define CDIM 64
#define NR 256
#define HID 256
#define EPS 1e-5f
#define SROW 258

__device__ __forceinline__ float b2f(bf16 v) { return __bfloat162float(v); }
__device__ __forceinline__ bf16 f2b(float v) { return __float2bfloat16(v); }
__device__ __forceinline__ short bfbits(float f) {
  bf16 h = __float2bfloat16(f);
  return __builtin_bit_cast(short, h);
}

__device__ __forceinline__ float wred_sum(float v) {
#pragma unroll
  for (int o = 32; o >= 1; o >>= 1) v += __shfl_xor(v, o);
  return v;
}

// ---------------- kernel 1: h = LN1(x) ----------------
__global__ __launch_bounds__(256) void k_ln1(
    const float* __restrict__ x, const float* __restrict__ g, const float* __restrict__ bb,
    bf16* __restrict__ h) {
  const int gid = blockIdx.x * 256 + threadIdx.x;
  const int lane = gid & 63;
  const size_t base = ((size_t)(gid >> 6)) << 6;
  const float xv = x[base + lane];
  const float mean = wred_sum(xv) * (1.f / 64.f);
  const float d = xv - mean;
  const float var = wred_sum(d * d) * (1.f / 64.f);
  h[base + lane] = f2b(d * rsqrtf(var + EPS) * g[lane] + bb[lane]);
}

// ---------------- kernel 2: 8x8/s8 conv + srnLN + kv projection ----------------
__global__ __launch_bounds__(256) void k_srconv(
    const bf16* __restrict__ h, const float* __restrict__ srw, const float* __restrict__ srb,
    const float* __restrict__ sng, const float* __restrict__ snb,
    const float* __restrict__ kvw, const float* __restrict__ kvb,
    bf16* __restrict__ kbuf, bf16* __restrict__ vbufT) {
  __shared__ bf16 pat[4][4096];
  const int tid = threadIdx.x;
  const int b = blockIdx.x >> 6;
  const int nr0 = (blockIdx.x & 63) << 2;
  for (int i = tid; i < 4 * 4096; i += 256) {
    const int pp = i >> 12, idx = i & 4095;
    const int sp = idx >> 6, ci = idx & 63;
    const int nr = nr0 + pp;
    const int py = nr >> 4, px = nr & 15;
    const int n = ((py << 3) + (sp >> 3)) * 128 + (px << 3) + (sp & 7);
    pat[pp][idx] = h[(((size_t)b * N_TOK) + n) * CDIM + ci];
  }
  __syncthreads();
  const int p = tid >> 6, co = tid & 63;
  float acc = srb[co];
#pragma unroll 8
  for (int k = 0; k < 4096; k++) {
    acc += b2f(pat[p][k]) * srw[k * 64 + co];
  }
  const float mean = wred_sum(acc) * (1.f / 64.f);
  const float d = acc - mean;
  const float var = wred_sum(d * d) * (1.f / 64.f);
  const float xn = d * rsqrtf(var + EPS) * sng[co] + snb[co];
  float ka = kvb[co];
  float va = kvb[64 + co];
#pragma unroll
  for (int ci = 0; ci < 64; ci++) {
    const float xv = __shfl(xn, ci);
    ka += xv * kvw[ci * 128 + co];
    va += xv * kvw[ci * 128 + 64 + co];
  }
  const int nr = nr0 + p;
  kbuf[(((size_t)b * NR) + nr) * CDIM + co] = f2b(ka);
  vbufT[(((size_t)b * CDIM) + co) * NR + nr] = f2b(va);  // transposed for attn B-frags
}

// ---------------- kernel 3: MFMA attention ----------------
// 2048 blocks x 256 thr; block = 64 queries of one batch, wave = 16 queries.
// LDS (shorts): [0,16384) K (256x64, chunk-XOR swizzle; reused for P after barrier)
//               [16384,32768) vT (64x256, swizzled)
//               [32768,36864) q/o scratch (per-wave 16x64, swizzled)
// swizzle: element (row, c) of a stride-S row -> row*S + ((c>>3 ^ (row&7))<<3) + (c&7)
__global__ __launch_bounds__(256) void k_attn(
    const bf16* __restrict__ h, const float* __restrict__ x,
    const float* __restrict__ qw, const float* __restrict__ qb,
    const bf16* __restrict__ kbuf, const bf16* __restrict__ vbufT,
    const float* __restrict__ pw, const float* __restrict__ pb,
    float* __restrict__ x2) {
  __shared__ __align__(16) short lds[36864];
  const int tid = threadIdx.x, lane = tid & 63, wv = tid >> 6;
  const int quad = lane >> 4, li = lane & 15;
  const int b = blockIdx.x >> 8;
  const int rowbase = ((blockIdx.x & 255) << 6) + (wv << 4);

  // stage K natural (256x64) and vT (64x256), both swizzled
#pragma unroll
  for (int it = 0; it < 8; it++) {
    const int idx = (it << 8) + tid;
    {
      const int row = idx >> 3, c8 = idx & 7;
      uint4 d = *(const uint4*)(kbuf + (((size_t)(b * 256 + row)) << 6) + (c8 << 3));
      *(uint4*)&lds[(row << 6) + ((c8 ^ (row & 7)) << 3)] = d;
    }
    {
      const int row = idx >> 5, c8 = idx & 31;
      uint4 d = *(const uint4*)(vbufT + (((size_t)(b * 64 + row)) << 8) + (c8 << 3));
      *(uint4*)&lds[16384 + (row << 8) + ((c8 ^ (row & 7)) << 3)] = d;
    }
  }

  // q_w B-frags from global (L2-cached), overlap with staging
  s8v qwf[2][4];
#pragma unroll
  for (int s = 0; s < 2; s++)
#pragma unroll
    for (int t = 0; t < 4; t++)
#pragma unroll
      for (int j = 0; j < 8; j++)
        qwf[s][t][j] = bfbits(qw[(((s << 5) + (quad << 3) + j) << 6) + (t << 4) + li]);

  // h A-frags straight from global (contiguous 16B per lane)
  const size_t hbase = (((size_t)(b * N_TOK + rowbase + li)) << 6) + (quad << 3);
  s8v ha[2];
  ha[0] = *(const s8v*)(h + hbase);
  ha[1] = *(const s8v*)(h + hbase + 32);

  // q = h @ qw + qb, then *0.125
  f4v qacc[4];
#pragma unroll
  for (int t = 0; t < 4; t++) {
    const float bv = qb[(t << 4) + li];
    qacc[t] = (f4v){bv, bv, bv, bv};
  }
#pragma unroll
  for (int s = 0; s < 2; s++)
#pragma unroll
    for (int t = 0; t < 4; t++)
      qacc[t] = __builtin_amdgcn_mfma_f32_16x16x32_bf16(ha[s], qwf[s][t], qacc[t], 0, 0, 0);

  // q C-layout -> LDS (A-layout source), per-wave private slice
  const int qoff = 32768 + (wv << 10);
#pragma unroll
  for (int t = 0; t < 4; t++)
#pragma unroll
    for (int r = 0; r < 4; r++) {
      const int m = (quad << 2) + r, c = (t << 4) + li;
      lds[qoff + (m << 6) + ((((c >> 3) ^ (m & 7)) << 3)) + (c & 7)] = bfbits(qacc[t][r] * 0.125f);
    }
  __syncthreads();  // staging visible to all waves

  s8v qa[2];
#pragma unroll
  for (int s = 0; s < 2; s++)
    qa[s] = *(const s8v*)&lds[qoff + (li << 6) + ((((s << 2) + quad) ^ (li & 7)) << 3)];

  // S = q @ K^T  (16 x 256 per wave, fp32)
  f4v sv[16];
#pragma unroll
  for (int t = 0; t < 16; t++) sv[t] = (f4v){0.f, 0.f, 0.f, 0.f};
#pragma unroll
  for (int t = 0; t < 16; t++)
#pragma unroll
    for (int s = 0; s < 2; s++) {
      s8v kb = *(const s8v*)&lds[(((t << 4) + li) << 6) + ((((s << 2) + quad) ^ (li & 7)) << 3)];
      sv[t] = __builtin_amdgcn_mfma_f32_16x16x32_bf16(qa[s], kb, sv[t], 0, 0, 0);
    }

  // softmax per row (row = quad*4+r; cols spread over 16 tiles x 16 lanes of the quad)
  float rl[4];
#pragma unroll
  for (int r = 0; r < 4; r++) {
    float mx = -1e30f;
#pragma unroll
    for (int t = 0; t < 16; t++) mx = fmaxf(mx, sv[t][r]);
#pragma unroll
    for (int o = 1; o <= 8; o <<= 1) mx = fmaxf(mx, __shfl_xor(mx, o));
    float sm = 0.f;
#pragma unroll
    for (int t = 0; t < 16; t++) {
      const float e = __expf(sv[t][r] - mx);
      sv[t][r] = e;
      sm += e;
    }
#pragma unroll
    for (int o = 1; o <= 8; o <<= 1) sm += __shfl_xor(sm, o);
    rl[r] = 1.0f / sm;
  }
  __syncthreads();  // all waves done reading K -> reuse its region for P

  // P (C-layout) -> LDS A-layout source, per-wave 16x256 slice
  const int poff = wv << 12;
#pragma unroll
  for (int t = 0; t < 16; t++)
#pragma unroll
    for (int r = 0; r < 4; r++) {
      const int m = (quad << 2) + r, c = (t << 4) + li;
      lds[poff + (m << 8) + (((c >> 3) ^ (m & 7)) << 3) + (c & 7)] = bfbits(sv[t][r]);
    }

  // O = P @ V
  f4v oacc[4];
#pragma unroll
  for (int t = 0; t < 4; t++) oacc[t] = (f4v){0.f, 0.f, 0.f, 0.f};
#pragma unroll
  for (int s = 0; s < 8; s++) {
    s8v pa = *(const s8v*)&lds[poff + (li << 8) + ((((s << 2) + quad) ^ (li & 7)) << 3)];
#pragma unroll
    for (int t = 0; t < 4; t++) {
      s8v vb = *(const s8v*)&lds[16384 + (((t << 4) + li) << 8) + ((((s << 2) + quad) ^ (li & 7)) << 3)];
      oacc[t] = __builtin_amdgcn_mfma_f32_16x16x32_bf16(pa, vb, oacc[t], 0, 0, 0);
    }
  }

  // O*1/l -> LDS (reuse q slice), then out-proj + residual
#pragma unroll
  for (int t = 0; t < 4; t++)
#pragma unroll
    for (int r = 0; r < 4; r++) {
      const int m = (quad << 2) + r, c = (t << 4) + li;
      lds[qoff + (m << 6) + (((c >> 3) ^ (m & 7)) << 3) + (c & 7)] = bfbits(oacc[t][r] * rl[r]);
    }
  s8v oa[2];
#pragma unroll
  for (int s = 0; s < 2; s++)
    oa[s] = *(const s8v*)&lds[qoff + (li << 6) + ((((s << 2) + quad) ^ (li & 7)) << 3)];

  f4v pacc[4];
#pragma unroll
  for (int t = 0; t < 4; t++) {
    const float bv = pb[(t << 4) + li];
    pacc[t] = (f4v){bv, bv, bv, bv};
  }
#pragma unroll
  for (int s = 0; s < 2; s++)
#pragma unroll
    for (int t = 0; t < 4; t++) {
      s8v wf;
#pragma unroll
      for (int j = 0; j < 8; j++)
        wf[j] = bfbits(pw[(((s << 5) + (quad << 3) + j) << 6) + (t << 4) + li]);
      pacc[t] = __builtin_amdgcn_mfma_f32_16x16x32_bf16(oa[s], wf, pacc[t], 0, 0, 0);
    }
#pragma unroll
  for (int t = 0; t < 4; t++)
#pragma unroll
    for (int r = 0; r < 4; r++) {
      const size_t gi = (((size_t)(b * N_TOK + rowbase + (quad << 2) + r)) << 6) + (t << 4) + li;
      x2[gi] = x[gi] + pacc[t][r];
    }
}

// ---------------- kernel 4: LN2 + fc1 ----------------
__global__ __launch_bounds__(256) void k_fc1(
    const float* __restrict__ x2, const float* __restrict__ g, const float* __restrict__ bb,
    const float* __restrict__ w1, const float* __restrict__ b1,
    bf16* __restrict__ f) {
  const int tid = threadIdx.x, lane = tid & 63;
  float wr[64];
#pragma unroll
  for (int c = 0; c < 64; c++) wr[c] = w1[c * HID + tid];
  const float bias = b1[tid];
  const float gl = g[lane], bl = bb[lane];
  const int r0 = blockIdx.x << 7;
  for (int r = 0; r < 128; r++) {
    const size_t base = ((size_t)(r0 + r)) << 6;
    const float xv = x2[base + lane];
    const float mean = wred_sum(xv) * (1.f / 64.f);
    const float d = xv - mean;
    const float var = wred_sum(d * d) * (1.f / 64.f);
    const float hn = d * rsqrtf(var + EPS) * gl + bl;
    float acc = bias;
#pragma unroll
    for (int c = 0; c < 64; c++) acc += __shfl(hn, c) * wr[c];
    f[((size_t)(r0 + r)) * HID + tid] = f2b(acc);
  }
}

// ---------------- kernel 5: dw 3x3 + gelu + fc2 + residual ----------------
__global__ __launch_bounds__(256) void k_out(
    const bf16* __restrict__ f, const float* __restrict__ dww,
    const float* __restrict__ x2,
    const float* __restrict__ w2, const float* __restrict__ fc2b,
    float* __restrict__ out) {
  __shared__ float gels[256];
  __shared__ float parts[4][64];
  const int tid = threadIdx.x, lane = tid & 63, wv = tid >> 6;
  float dwr[9];
#pragma unroll
  for (int i = 0; i < 9; i++) dwr[i] = dww[i * HID + tid];
  float wr[64];
#pragma unroll
  for (int c = 0; c < 64; c++) wr[c] = w2[(wv * 64 + c) * CDIM + lane];
  const float bias = fc2b[lane];
  const int r0 = blockIdx.x << 7;
  for (int r = 0; r < 128; r++) {
    const int row = r0 + r;
    const int bb = row >> 14;
    const int n = row & 16383;
    const int y = n >> 7, xw = n & 127;
    float acc = 0.f;
#pragma unroll
    for (int dy = 0; dy < 3; dy++) {
      const int yy = y + dy - 1;
      if (yy < 0 || yy > 127) continue;
#pragma unroll
      for (int dx = 0; dx < 3; dx++) {
        const int xx = xw + dx - 1;
        if (xx < 0 || xx > 127) continue;
        acc += b2f(f[((((size_t)bb << 14) + (yy << 7) + xx) << 8) + tid]) * dwr[dy * 3 + dx];
      }
    }
    const float ge = 0.5f * acc * (1.f + erff(acc * 0.70710678118654752f));
    gels[tid] = ge;
    __syncthreads();
    float oa = 0.f;
#pragma unroll
    for (int c = 0; c < 64; c++) oa += gels[(wv << 6) + c] * wr[c];
    parts[wv][lane] = oa;
    __syncthreads();
    if (wv == 0) {
      const float t = parts[0][lane] + parts[1][lane] + parts[2][lane] + parts[3][lane]
                      + bias + x2[((size_t)row << 6) + lane];
      out[((size_t)row << 6) + lane] = t;
    }
    __syncthreads();
  }
}

extern "C" void kernel_launch(void* const* d_in, const int* in_sizes, int n_in,
                              void* d_out, int out_size, void* d_ws, size_t ws_size,
                              hipStream_t stream) {
  const float* x    = (const float*)d_in[0];
  const float* ln1g = (const float*)d_in[3];
  const float* ln1b = (const float*)d_in[4];
  const float* qw   = (const float*)d_in[5];
  const float* qb   = (const float*)d_in[6];
  const float* kvw  = (const float*)d_in[7];
  const float* kvb  = (const float*)d_in[8];
  const float* pw   = (const float*)d_in[9];
  const float* pb   = (const float*)d_in[10];
  const float* srw  = (const float*)d_in[11];
  const float* srb  = (const float*)d_in[12];
  const float* sng  = (const float*)d_in[13];
  const float* snb  = (const float*)d_in[14];
  const float* ln2g = (const float*)d_in[15];
  const float* ln2b = (const float*)d_in[16];
  const float* w1   = (const float*)d_in[17];
  const float* b1   = (const float*)d_in[18];
  const float* dww  = (const float*)d_in[19];
  const float* w2   = (const float*)d_in[20];
  const float* b2v  = (const float*)d_in[21];
  float* out = (float*)d_out;

  char* ws = (char*)d_ws;
  float* x2    = (float*)ws;                   // 33,554,432 B
  bf16*  h     = (bf16*)(ws + 33554432);       // 16,777,216 B
  bf16*  kbuf  = (bf16*)(ws + 50331648);       //    262,144 B
  bf16*  vbufT = (bf16*)(ws + 50593792);       //    262,144 B
  bf16*  fbuf  = (bf16*)(ws + 50855936);       // 67,108,864 B

  k_ln1   <<<32768, 256, 0, stream>>>(x, ln1g, ln1b, h);
  k_srconv<<<  512, 256, 0, stream>>>(h, srw, srb, sng, snb, kvw, kvb, kbuf, vbufT);
  k_attn  <<< 2048, 256, 0, stream>>>(h, x, qw, qb, kbuf, vbufT, pw, pb, x2);
  k_fc1   <<< 1024, 256, 0, stream>>>(x2, ln2g, ln2b, w1, b1, fbuf);
  k_out   <<< 1024, 256, 0, stream>>>(fbuf, dww, x2, w2, b2v, out);
}

// Round 4
// 398.084 us; speedup vs baseline: 6.0493x; 2.8807x over previous
//
#include <hip/hip_runtime.h>
#include <hip/hip_bf16.h>

// SegFormer block. R3: MFMA fc1 + MFMA fc2/dw-conv restructure + prepped
// bf16 transposed/swizzled weights + bf16 x2 residual stream.
// Workspace layout (all offsets 16B aligned; total 101,269,504 <= ws):
//   [0,         16777216)  x2    bf16 (B,N,C)
//   [16777216,  33554432)  h     bf16 (B,N,C)
//   [33554432,  33816576)  k     bf16 (B,Nr,C)
//   [33816576,  34078720)  vT    bf16 (B,C,Nr)
//   [34078720, 101187584)  f     bf16 (B,N,HID)
//   [101187584,101220352)  w1T   bf16 [n=256][k=64]  swizzled
//   [101220352,101253120)  w2T   bf16 [n=64][k=256]  swizzled
//   [101253120,101261312)  qwT   bf16 [n=64][k=64]   swizzled
//   [101261312,101269504)  pwT   bf16 [n=64][k=64]   swizzled
// swizzle: short at (row n, ch k) -> n*K + ((k>>3 ^ (n&7))<<3) + (k&7)

typedef __hip_bfloat16 bf16;
typedef __hip_bfloat162 bf162;
typedef __attribute__((ext_vector_type(8))) short s8v;
typedef __attribute__((ext_vector_type(4))) float f4v;

#define N_TOK 16384
#define CDIM 64
#define NR 256
#define HID 256
#define EPS 1e-5f

__device__ __forceinline__ float b2f(bf16 v) { return __bfloat162float(v); }
__device__ __forceinline__ bf16 f2b(float v) { return __float2bfloat16(v); }
__device__ __forceinline__ short bfbits(float f) {
  bf16 h = __float2bfloat16(f);
  return __builtin_bit_cast(short, h);
}
__device__ __forceinline__ float bits2f(short s) {
  return b2f(__builtin_bit_cast(bf16, s));
}

__device__ __forceinline__ float wred_sum(float v) {
#pragma unroll
  for (int o = 32; o >= 1; o >>= 1) v += __shfl_xor(v, o);
  return v;
}

// ---------------- kernel 0: weight prep (bf16 transpose + swizzle) ----------------
// 160 blocks x 256 thr, one element each.
__global__ __launch_bounds__(256) void k_prep(
    const float* __restrict__ qw, const float* __restrict__ pw,
    const float* __restrict__ w1, const float* __restrict__ w2,
    bf16* __restrict__ qwT, bf16* __restrict__ pwT,
    bf16* __restrict__ w1T, bf16* __restrict__ w2T) {
  int id = blockIdx.x * 256 + threadIdx.x;
  if (id < 4096) {
    const int n = id >> 6, k = id & 63;
    qwT[(n << 6) + ((((k >> 3) ^ (n & 7)) << 3)) + (k & 7)] = f2b(qw[(k << 6) + n]);
  } else if (id < 8192) {
    id -= 4096;
    const int n = id >> 6, k = id & 63;
    pwT[(n << 6) + ((((k >> 3) ^ (n & 7)) << 3)) + (k & 7)] = f2b(pw[(k << 6) + n]);
  } else if (id < 24576) {
    id -= 8192;
    const int n = id >> 6, k = id & 63;   // n in [0,256), k in [0,64)
    w1T[(n << 6) + ((((k >> 3) ^ (n & 7)) << 3)) + (k & 7)] = f2b(w1[(k << 8) + n]);
  } else {
    id -= 24576;
    const int n = id >> 8, k = id & 255;  // n in [0,64), k in [0,256)
    w2T[(n << 8) + ((((k >> 3) ^ (n & 7)) << 3)) + (k & 7)] = f2b(w2[(k << 6) + n]);
  }
}

// ---------------- kernel 1: h = LN1(x) ----------------
__global__ __launch_bounds__(256) void k_ln1(
    const float* __restrict__ x, const float* __restrict__ g, const float* __restrict__ bb,
    bf16* __restrict__ h) {
  const int gid = blockIdx.x * 256 + threadIdx.x;
  const int lane = gid & 63;
  const size_t base = ((size_t)(gid >> 6)) << 6;
  const float xv = x[base + lane];
  const float mean = wred_sum(xv) * (1.f / 64.f);
  const float d = xv - mean;
  const float var = wred_sum(d * d) * (1.f / 64.f);
  h[base + lane] = f2b(d * rsqrtf(var + EPS) * g[lane] + bb[lane]);
}

// ---------------- kernel 2: 8x8/s8 conv + srnLN + kv projection ----------------
__global__ __launch_bounds__(256) void k_srconv(
    const bf16* __restrict__ h, const float* __restrict__ srw, const float* __restrict__ srb,
    const float* __restrict__ sng, const float* __restrict__ snb,
    const float* __restrict__ kvw, const float* __restrict__ kvb,
    bf16* __restrict__ kbuf, bf16* __restrict__ vbufT) {
  __shared__ bf16 pat[4][4096];
  const int tid = threadIdx.x;
  const int b = blockIdx.x >> 6;
  const int nr0 = (blockIdx.x & 63) << 2;
  for (int i = tid; i < 4 * 4096; i += 256) {
    const int pp = i >> 12, idx = i & 4095;
    const int sp = idx >> 6, ci = idx & 63;
    const int nr = nr0 + pp;
    const int py = nr >> 4, px = nr & 15;
    const int n = ((py << 3) + (sp >> 3)) * 128 + (px << 3) + (sp & 7);
    pat[pp][idx] = h[(((size_t)b * N_TOK) + n) * CDIM + ci];
  }
  __syncthreads();
  const int p = tid >> 6, co = tid & 63;
  float acc = srb[co];
#pragma unroll 8
  for (int k = 0; k < 4096; k++) {
    acc += b2f(pat[p][k]) * srw[k * 64 + co];
  }
  const float mean = wred_sum(acc) * (1.f / 64.f);
  const float d = acc - mean;
  const float var = wred_sum(d * d) * (1.f / 64.f);
  const float xn = d * rsqrtf(var + EPS) * sng[co] + snb[co];
  float ka = kvb[co];
  float va = kvb[64 + co];
#pragma unroll
  for (int ci = 0; ci < 64; ci++) {
    const float xv = __shfl(xn, ci);
    ka += xv * kvw[ci * 128 + co];
    va += xv * kvw[ci * 128 + 64 + co];
  }
  const int nr = nr0 + p;
  kbuf[(((size_t)b * NR) + nr) * CDIM + co] = f2b(ka);
  vbufT[(((size_t)b * CDIM) + co) * NR + nr] = f2b(va);
}

// ---------------- kernel 3: MFMA attention ----------------
__global__ __launch_bounds__(256) void k_attn(
    const bf16* __restrict__ h, const float* __restrict__ x,
    const bf16* __restrict__ qwT, const float* __restrict__ qb,
    const bf16* __restrict__ kbuf, const bf16* __restrict__ vbufT,
    const bf16* __restrict__ pwT, const float* __restrict__ pb,
    bf16* __restrict__ x2) {
  __shared__ __align__(16) short lds[36864];
  const int tid = threadIdx.x, lane = tid & 63, wv = tid >> 6;
  const int quad = lane >> 4, li = lane & 15;
  const int b = blockIdx.x >> 8;
  const int rowbase = ((blockIdx.x & 255) << 6) + (wv << 4);

#pragma unroll
  for (int it = 0; it < 8; it++) {
    const int idx = (it << 8) + tid;
    {
      const int row = idx >> 3, c8 = idx & 7;
      uint4 d = *(const uint4*)(kbuf + (((size_t)(b * 256 + row)) << 6) + (c8 << 3));
      *(uint4*)&lds[(row << 6) + ((c8 ^ (row & 7)) << 3)] = d;
    }
    {
      const int row = idx >> 5, c8 = idx & 31;
      uint4 d = *(const uint4*)(vbufT + (((size_t)(b * 64 + row)) << 8) + (c8 << 3));
      *(uint4*)&lds[16384 + (row << 8) + ((c8 ^ (row & 7)) << 3)] = d;
    }
  }

  // q_w B-frags: 16B swizzled loads from prepped qwT
  s8v qwf[2][4];
#pragma unroll
  for (int s = 0; s < 2; s++)
#pragma unroll
    for (int t = 0; t < 4; t++) {
      const int n = (t << 4) + li;
      qwf[s][t] = *(const s8v*)(qwT + (n << 6) + ((((s << 2) + quad) ^ (n & 7)) << 3));
    }

  const size_t hbase = (((size_t)(b * N_TOK + rowbase + li)) << 6) + (quad << 3);
  s8v ha[2];
  ha[0] = *(const s8v*)(h + hbase);
  ha[1] = *(const s8v*)(h + hbase + 32);

  f4v qacc[4];
#pragma unroll
  for (int t = 0; t < 4; t++) {
    const float bv = qb[(t << 4) + li];
    qacc[t] = (f4v){bv, bv, bv, bv};
  }
#pragma unroll
  for (int s = 0; s < 2; s++)
#pragma unroll
    for (int t = 0; t < 4; t++)
      qacc[t] = __builtin_amdgcn_mfma_f32_16x16x32_bf16(ha[s], qwf[s][t], qacc[t], 0, 0, 0);

  const int qoff = 32768 + (wv << 10);
#pragma unroll
  for (int t = 0; t < 4; t++)
#pragma unroll
    for (int r = 0; r < 4; r++) {
      const int m = (quad << 2) + r, c = (t << 4) + li;
      lds[qoff + (m << 6) + ((((c >> 3) ^ (m & 7)) << 3)) + (c & 7)] = bfbits(qacc[t][r] * 0.125f);
    }
  __syncthreads();

  s8v qa[2];
#pragma unroll
  for (int s = 0; s < 2; s++)
    qa[s] = *(const s8v*)&lds[qoff + (li << 6) + ((((s << 2) + quad) ^ (li & 7)) << 3)];

  f4v sv[16];
#pragma unroll
  for (int t = 0; t < 16; t++) sv[t] = (f4v){0.f, 0.f, 0.f, 0.f};
#pragma unroll
  for (int t = 0; t < 16; t++)
#pragma unroll
    for (int s = 0; s < 2; s++) {
      s8v kb = *(const s8v*)&lds[(((t << 4) + li) << 6) + ((((s << 2) + quad) ^ (li & 7)) << 3)];
      sv[t] = __builtin_amdgcn_mfma_f32_16x16x32_bf16(qa[s], kb, sv[t], 0, 0, 0);
    }

  float rl[4];
#pragma unroll
  for (int r = 0; r < 4; r++) {
    float mx = -1e30f;
#pragma unroll
    for (int t = 0; t < 16; t++) mx = fmaxf(mx, sv[t][r]);
#pragma unroll
    for (int o = 1; o <= 8; o <<= 1) mx = fmaxf(mx, __shfl_xor(mx, o));
    float sm = 0.f;
#pragma unroll
    for (int t = 0; t < 16; t++) {
      const float e = __expf(sv[t][r] - mx);
      sv[t][r] = e;
      sm += e;
    }
#pragma unroll
    for (int o = 1; o <= 8; o <<= 1) sm += __shfl_xor(sm, o);
    rl[r] = 1.0f / sm;
  }
  __syncthreads();

  const int poff = wv << 12;
#pragma unroll
  for (int t = 0; t < 16; t++)
#pragma unroll
    for (int r = 0; r < 4; r++) {
      const int m = (quad << 2) + r, c = (t << 4) + li;
      lds[poff + (m << 8) + (((c >> 3) ^ (m & 7)) << 3) + (c & 7)] = bfbits(sv[t][r]);
    }

  f4v oacc[4];
#pragma unroll
  for (int t = 0; t < 4; t++) oacc[t] = (f4v){0.f, 0.f, 0.f, 0.f};
#pragma unroll
  for (int s = 0; s < 8; s++) {
    s8v pa = *(const s8v*)&lds[poff + (li << 8) + ((((s << 2) + quad) ^ (li & 7)) << 3)];
#pragma unroll
    for (int t = 0; t < 4; t++) {
      s8v vb = *(const s8v*)&lds[16384 + (((t << 4) + li) << 8) + ((((s << 2) + quad) ^ (li & 7)) << 3)];
      oacc[t] = __builtin_amdgcn_mfma_f32_16x16x32_bf16(pa, vb, oacc[t], 0, 0, 0);
    }
  }

#pragma unroll
  for (int t = 0; t < 4; t++)
#pragma unroll
    for (int r = 0; r < 4; r++) {
      const int m = (quad << 2) + r, c = (t << 4) + li;
      lds[qoff + (m << 6) + (((c >> 3) ^ (m & 7)) << 3) + (c & 7)] = bfbits(oacc[t][r] * rl[r]);
    }
  s8v oa[2];
#pragma unroll
  for (int s = 0; s < 2; s++)
    oa[s] = *(const s8v*)&lds[qoff + (li << 6) + ((((s << 2) + quad) ^ (li & 7)) << 3)];

  f4v pacc[4];
#pragma unroll
  for (int t = 0; t < 4; t++) {
    const float bv = pb[(t << 4) + li];
    pacc[t] = (f4v){bv, bv, bv, bv};
  }
#pragma unroll
  for (int s = 0; s < 2; s++)
#pragma unroll
    for (int t = 0; t < 4; t++) {
      const int n = (t << 4) + li;
      s8v wf = *(const s8v*)(pwT + (n << 6) + ((((s << 2) + quad) ^ (n & 7)) << 3));
      pacc[t] = __builtin_amdgcn_mfma_f32_16x16x32_bf16(oa[s], wf, pacc[t], 0, 0, 0);
    }
#pragma unroll
  for (int t = 0; t < 4; t++)
#pragma unroll
    for (int r = 0; r < 4; r++) {
      const size_t gi = (((size_t)(b * N_TOK + rowbase + (quad << 2) + r)) << 6) + (t << 4) + li;
      x2[gi] = f2b(x[gi] + pacc[t][r]);
    }
}

// ---------------- kernel 4: LN2 + fc1 (MFMA) ----------------
// 2048 blocks x 256 thr; block = 64 rows x 256 cols.
__global__ __launch_bounds__(256) void k_fc1(
    const bf16* __restrict__ x2, const float* __restrict__ g, const float* __restrict__ bb,
    const bf16* __restrict__ w1T, const float* __restrict__ b1,
    bf16* __restrict__ f) {
  __shared__ __align__(16) short hs[4096];  // 64x64 A-tile, swizzled
  const int tid = threadIdx.x, lane = tid & 63, wv = tid >> 6;
  const int quad = lane >> 4, li = lane & 15;
  const int r0 = blockIdx.x << 6;

  // B-frags + bias (global, L2-hot), overlap with LN
  s8v wf[2][4];
  float bv[4];
#pragma unroll
  for (int t = 0; t < 4; t++) {
    const int n = (((wv << 2) + t) << 4) + li;
    bv[t] = b1[n];
#pragma unroll
    for (int s = 0; s < 2; s++)
      wf[s][t] = *(const s8v*)(w1T + (n << 6) + ((((s << 2) + quad) ^ (n & 7)) << 3));
  }

  // LN: 4 threads per row, 16 ch each
  const int row = tid >> 2, q4 = tid & 3;
  const bf16* xp = x2 + (((size_t)(r0 + row)) << 6) + (q4 << 4);
  s8v xa = *(const s8v*)xp;
  s8v xb = *(const s8v*)(xp + 8);
  float v[16];
#pragma unroll
  for (int j = 0; j < 8; j++) {
    v[j] = bits2f(xa[j]);
    v[8 + j] = bits2f(xb[j]);
  }
  float s = 0.f;
#pragma unroll
  for (int j = 0; j < 16; j++) s += v[j];
  s += __shfl_xor(s, 1); s += __shfl_xor(s, 2);
  const float mean = s * (1.f / 64.f);
  float vs = 0.f;
#pragma unroll
  for (int j = 0; j < 16; j++) { v[j] -= mean; vs += v[j] * v[j]; }
  vs += __shfl_xor(vs, 1); vs += __shfl_xor(vs, 2);
  const float rs = rsqrtf(vs * (1.f / 64.f) + EPS);
  s8v p0, p1;
#pragma unroll
  for (int j = 0; j < 16; j++) {
    const int c = (q4 << 4) + j;
    const short hb = bfbits(v[j] * rs * g[c] + bb[c]);
    if (j < 8) p0[j] = hb; else p1[j - 8] = hb;
  }
  {
    const int m7 = row & 7;
    *(s8v*)&hs[(row << 6) + (((q4 << 1) ^ m7) << 3)] = p0;
    *(s8v*)&hs[(row << 6) + ((((q4 << 1) + 1) ^ m7) << 3)] = p1;
  }
  __syncthreads();

  s8v qa[4][2];
#pragma unroll
  for (int rg = 0; rg < 4; rg++) {
    const int m = (rg << 4) + li;
#pragma unroll
    for (int s2 = 0; s2 < 2; s2++)
      qa[rg][s2] = *(const s8v*)&hs[(m << 6) + ((((s2 << 2) + quad) ^ (m & 7)) << 3)];
  }
  f4v acc[4][4];
#pragma unroll
  for (int rg = 0; rg < 4; rg++)
#pragma unroll
    for (int t = 0; t < 4; t++) acc[rg][t] = (f4v){bv[t], bv[t], bv[t], bv[t]};
#pragma unroll
  for (int rg = 0; rg < 4; rg++)
#pragma unroll
    for (int t = 0; t < 4; t++) {
      acc[rg][t] = __builtin_amdgcn_mfma_f32_16x16x32_bf16(qa[rg][0], wf[0][t], acc[rg][t], 0, 0, 0);
      acc[rg][t] = __builtin_amdgcn_mfma_f32_16x16x32_bf16(qa[rg][1], wf[1][t], acc[rg][t], 0, 0, 0);
    }
#pragma unroll
  for (int rg = 0; rg < 4; rg++)
#pragma unroll
    for (int t = 0; t < 4; t++)
#pragma unroll
      for (int r = 0; r < 4; r++) {
        const int rr = r0 + (rg << 4) + (quad << 2) + r;
        f[((size_t)rr << 8) + ((((wv << 2) + t) << 4)) + li] = f2b(acc[rg][t][r]);
      }
}

// ---------------- kernel 5: dw 3x3 + gelu + fc2 (MFMA) + residual ----------------
// 2048 blocks x 256 thr; block = 64 tokens (one y, half-row xh).
__global__ __launch_bounds__(256) void k_out(
    const bf16* __restrict__ f, const float* __restrict__ dww,
    const bf16* __restrict__ x2, const bf16* __restrict__ w2T,
    const float* __restrict__ fc2b, float* __restrict__ out) {
  __shared__ __align__(16) short gs[16384];   // 64x256 A-tile, swizzled
  __shared__ __align__(16) short w2s[16384];  // w2T copy (pre-swizzled)
  const int tid = threadIdx.x, lane = tid & 63, wv = tid >> 6;
  const int quad = lane >> 4, li = lane & 15;
  const int b = blockIdx.x >> 8;
  const int y = (blockIdx.x >> 1) & 127;
  const int xh = blockIdx.x & 1;

#pragma unroll
  for (int i = 0; i < 8; i++)
    ((uint4*)w2s)[(i << 8) + tid] = ((const uint4*)w2T)[(i << 8) + tid];

  // dw conv: thread = 4 consecutive x tokens x 16 channels
  const int tg = tid & 15, cg = tid >> 4;
  float acc[4][16];
#pragma unroll
  for (int t = 0; t < 4; t++)
#pragma unroll
    for (int j = 0; j < 16; j++) acc[t][j] = 0.f;

  const int x0 = (xh << 6) + (tg << 2);
  for (int dy = 0; dy < 3; dy++) {
    const int yy = y + dy - 1;
    if (yy < 0 || yy > 127) continue;   // block-uniform branch
    float dwr[3][16];
#pragma unroll
    for (int dx = 0; dx < 3; dx++) {
      const float4* wp = (const float4*)(dww + (dy * 3 + dx) * HID + (cg << 4));
#pragma unroll
      for (int j4 = 0; j4 < 4; j4++) {
        const float4 w4 = wp[j4];
        dwr[dx][j4 * 4 + 0] = w4.x; dwr[dx][j4 * 4 + 1] = w4.y;
        dwr[dx][j4 * 4 + 2] = w4.z; dwr[dx][j4 * 4 + 3] = w4.w;
      }
    }
#pragma unroll
    for (int xi = -1; xi <= 4; xi++) {
      const int xx = x0 + xi;
      if (xx < 0 || xx > 127) continue;  // diverges only at image edge lanes
      const bf16* fp = f + (((((size_t)(b * 128 + yy)) << 7) + xx) << 8) + (cg << 4);
      s8v fa = *(const s8v*)fp;
      s8v fb = *(const s8v*)(fp + 8);
      float fv[16];
#pragma unroll
      for (int j = 0; j < 8; j++) { fv[j] = bits2f(fa[j]); fv[8 + j] = bits2f(fb[j]); }
#pragma unroll
      for (int dx = 0; dx < 3; dx++) {
        const int t = xi - dx + 1;
        if (t < 0 || t > 3) continue;    // compile-time (xi, dx unrolled)
#pragma unroll
        for (int j = 0; j < 16; j++) acc[t][j] += fv[j] * dwr[dx][j];
      }
    }
  }

  // gelu(exact) -> swizzled LDS A-tile
#pragma unroll
  for (int t = 0; t < 4; t++) {
    const int m = (tg << 2) + t;
    s8v p0, p1;
#pragma unroll
    for (int j = 0; j < 16; j++) {
      const float a = acc[t][j];
      const float ge = 0.5f * a * (1.f + erff(a * 0.70710678118654752f));
      if (j < 8) p0[j] = bfbits(ge); else p1[j - 8] = bfbits(ge);
    }
    const int m7 = m & 7;
    *(s8v*)&gs[(m << 8) + (((cg << 1) ^ m7) << 3)] = p0;
    *(s8v*)&gs[(m << 8) + ((((cg << 1) + 1) ^ m7) << 3)] = p1;
  }
  __syncthreads();

  // fc2: C 64x64; wave = row-group, 4 col-tiles
  f4v oa2[4];
#pragma unroll
  for (int ct = 0; ct < 4; ct++) {
    const float bb2 = fc2b[(ct << 4) + li];
    oa2[ct] = (f4v){bb2, bb2, bb2, bb2};
  }
  const int m = (wv << 4) + li;
#pragma unroll
  for (int kc = 0; kc < 8; kc++) {
    const int ch = (kc << 2) + quad;
    s8v av = *(const s8v*)&gs[(m << 8) + ((ch ^ (m & 7)) << 3)];
#pragma unroll
    for (int ct = 0; ct < 4; ct++) {
      const int n = (ct << 4) + li;
      s8v bv2 = *(const s8v*)&w2s[(n << 8) + ((ch ^ (n & 7)) << 3)];
      oa2[ct] = __builtin_amdgcn_mfma_f32_16x16x32_bf16(av, bv2, oa2[ct], 0, 0, 0);
    }
  }
  const int tokbase = (b << 14) + (y << 7) + (xh << 6) + (wv << 4) + (quad << 2);
#pragma unroll
  for (int ct = 0; ct < 4; ct++)
#pragma unroll
    for (int r = 0; r < 4; r++) {
      const size_t gi = (((size_t)(tokbase + r)) << 6) + (ct << 4) + li;
      out[gi] = b2f(x2[gi]) + oa2[ct][r];
    }
}

extern "C" void kernel_launch(void* const* d_in, const int* in_sizes, int n_in,
                              void* d_out, int out_size, void* d_ws, size_t ws_size,
                              hipStream_t stream) {
  const float* x    = (const float*)d_in[0];
  const float* ln1g = (const float*)d_in[3];
  const float* ln1b = (const float*)d_in[4];
  const float* qw   = (const float*)d_in[5];
  const float* qb   = (const float*)d_in[6];
  const float* kvw  = (const float*)d_in[7];
  const float* kvb  = (const float*)d_in[8];
  const float* pw   = (const float*)d_in[9];
  const float* pb   = (const float*)d_in[10];
  const float* srw  = (const float*)d_in[11];
  const float* srb  = (const float*)d_in[12];
  const float* sng  = (const float*)d_in[13];
  const float* snb  = (const float*)d_in[14];
  const float* ln2g = (const float*)d_in[15];
  const float* ln2b = (const float*)d_in[16];
  const float* w1   = (const float*)d_in[17];
  const float* b1   = (const float*)d_in[18];
  const float* dww  = (const float*)d_in[19];
  const float* w2   = (const float*)d_in[20];
  const float* b2v  = (const float*)d_in[21];
  float* out = (float*)d_out;

  char* ws = (char*)d_ws;
  bf16* x2    = (bf16*)ws;                    // 16,777,216 B
  bf16* h     = (bf16*)(ws + 16777216);       // 16,777,216 B
  bf16* kbuf  = (bf16*)(ws + 33554432);       //    262,144 B
  bf16* vbufT = (bf16*)(ws + 33816576);       //    262,144 B
  bf16* fbuf  = (bf16*)(ws + 34078720);       // 67,108,864 B
  bf16* w1T   = (bf16*)(ws + 101187584);      //     32,768 B
  bf16* w2T   = (bf16*)(ws + 101220352);      //     32,768 B
  bf16* qwT   = (bf16*)(ws + 101253120);      //      8,192 B
  bf16* pwT   = (bf16*)(ws + 101261312);      //      8,192 B

  k_prep  <<<  160, 256, 0, stream>>>(qw, pw, w1, w2, qwT, pwT, w1T, w2T);
  k_ln1   <<<32768, 256, 0, stream>>>(x, ln1g, ln1b, h);
  k_srconv<<<  512, 256, 0, stream>>>(h, srw, srb, sng, snb, kvw, kvb, kbuf, vbufT);
  k_attn  <<< 2048, 256, 0, stream>>>(h, x, qwT, qb, kbuf, vbufT, pwT, pb, x2);
  k_fc1   <<< 2048, 256, 0, stream>>>(x2, ln2g, ln2b, w1T, b1, fbuf);
  k_out   <<< 2048, 256, 0, stream>>>(fbuf, dww, x2, w2T, b2v, out);
}

// Round 5
// 256.724 us; speedup vs baseline: 9.3802x; 1.5506x over previous
//
#include <hip/hip_runtime.h>
#include <hip/hip_bf16.h>

// SegFormer block. R4: sr-conv as MFMA GEMM (direct-global A/B frags, 8-way
// K-split + separate reduce/LN/kv kernel); vectorized LN1.
// Workspace layout (total 105,988,096 <= ws):
//   [0,         16777216)  x2    bf16 (B,N,C)
//   [16777216,  33554432)  h     bf16 (B,N,C)
//   [33554432,  33816576)  k     bf16 (B,Nr,C)
//   [33816576,  34078720)  vT    bf16 (B,C,Nr)
//   [34078720, 101187584)  f     bf16 (B,N,HID)
//   [101187584,101220352)  w1T   bf16 [n=256][k=64]  swizzled
//   [101220352,101253120)  w2T   bf16 [n=64][k=256]  swizzled
//   [101253120,101261312)  qwT   bf16 [n=64][k=64]   swizzled
//   [101261312,101269504)  pwT   bf16 [n=64][k=64]   swizzled
//   [101269504,101793792)  srwT  bf16 [n=64][k=4096] NOT swizzled
//   [101793792,105988096)  part  fp32 [8][2048][64]  sr-conv K-split partials
// swizzle: short at (row n, ch k) -> n*K + ((k>>3 ^ (n&7))<<3) + (k&7)

typedef __hip_bfloat16 bf16;
typedef __hip_bfloat162 bf162;
typedef __attribute__((ext_vector_type(8))) short s8v;
typedef __attribute__((ext_vector_type(4))) float f4v;

#define N_TOK 16384
#define CDIM 64
#define NR 256
#define HID 256
#define EPS 1e-5f

__device__ __forceinline__ float b2f(bf16 v) { return __bfloat162float(v); }
__device__ __forceinline__ bf16 f2b(float v) { return __float2bfloat16(v); }
__device__ __forceinline__ short bfbits(float f) {
  bf16 h = __float2bfloat16(f);
  return __builtin_bit_cast(short, h);
}
__device__ __forceinline__ float bits2f(short s) {
  return b2f(__builtin_bit_cast(bf16, s));
}

__device__ __forceinline__ float wred_sum(float v) {
#pragma unroll
  for (int o = 32; o >= 1; o >>= 1) v += __shfl_xor(v, o);
  return v;
}

// ---------------- kernel 0: weight prep ----------------
// 1184 blocks x 256 thr, one element each.
__global__ __launch_bounds__(256) void k_prep(
    const float* __restrict__ qw, const float* __restrict__ pw,
    const float* __restrict__ w1, const float* __restrict__ w2,
    const float* __restrict__ srw,
    bf16* __restrict__ qwT, bf16* __restrict__ pwT,
    bf16* __restrict__ w1T, bf16* __restrict__ w2T,
    bf16* __restrict__ srwT) {
  int id = blockIdx.x * 256 + threadIdx.x;
  if (id < 4096) {
    const int n = id >> 6, k = id & 63;
    qwT[(n << 6) + ((((k >> 3) ^ (n & 7)) << 3)) + (k & 7)] = f2b(qw[(k << 6) + n]);
  } else if (id < 8192) {
    id -= 4096;
    const int n = id >> 6, k = id & 63;
    pwT[(n << 6) + ((((k >> 3) ^ (n & 7)) << 3)) + (k & 7)] = f2b(pw[(k << 6) + n]);
  } else if (id < 24576) {
    id -= 8192;
    const int n = id >> 6, k = id & 63;   // n in [0,256), k in [0,64)
    w1T[(n << 6) + ((((k >> 3) ^ (n & 7)) << 3)) + (k & 7)] = f2b(w1[(k << 8) + n]);
  } else if (id < 40960) {
    id -= 24576;
    const int n = id >> 8, k = id & 255;  // n in [0,64), k in [0,256)
    w2T[(n << 8) + ((((k >> 3) ^ (n & 7)) << 3)) + (k & 7)] = f2b(w2[(k << 6) + n]);
  } else {
    id -= 40960;                          // [0, 262144)
    const int n = id >> 12, k = id & 4095;
    srwT[(n << 12) + k] = f2b(srw[(k << 6) + n]);
  }
}

// ---------------- kernel 1: h = LN1(x), vectorized ----------------
// 2048 blocks x 256 thr; 4 threads per token, 16 ch each.
__global__ __launch_bounds__(256) void k_ln1(
    const float* __restrict__ x, const float* __restrict__ g, const float* __restrict__ bb,
    bf16* __restrict__ h) {
  const int tid = threadIdx.x;
  const int row = (blockIdx.x << 6) + (tid >> 2), q4 = tid & 3;
  const float4* xp = (const float4*)(x + (((size_t)row) << 6) + (q4 << 4));
  float v[16];
#pragma unroll
  for (int j4 = 0; j4 < 4; j4++) {
    const float4 a = xp[j4];
    v[j4 * 4 + 0] = a.x; v[j4 * 4 + 1] = a.y; v[j4 * 4 + 2] = a.z; v[j4 * 4 + 3] = a.w;
  }
  float s = 0.f;
#pragma unroll
  for (int j = 0; j < 16; j++) s += v[j];
  s += __shfl_xor(s, 1); s += __shfl_xor(s, 2);
  const float mean = s * (1.f / 64.f);
  float vs = 0.f;
#pragma unroll
  for (int j = 0; j < 16; j++) { v[j] -= mean; vs += v[j] * v[j]; }
  vs += __shfl_xor(vs, 1); vs += __shfl_xor(vs, 2);
  const float rs = rsqrtf(vs * (1.f / 64.f) + EPS);
  s8v p0, p1;
#pragma unroll
  for (int j = 0; j < 16; j++) {
    const int c = (q4 << 4) + j;
    const short hb = bfbits(v[j] * rs * g[c] + bb[c]);
    if (j < 8) p0[j] = hb; else p1[j - 8] = hb;
  }
  bf16* hp = h + (((size_t)row) << 6) + (q4 << 4);
  *(s8v*)hp = p0;
  *(s8v*)(hp + 8) = p1;
}

// ---------------- kernel 2a: sr-conv GEMM (MFMA, 8-way K-split) ----------------
// 256 blocks x 256 thr = 32 row-tiles (64 patches each) x 8 K-chunks (512 K each).
// A (patch rows x K) direct from h: for k = sp*64+ci, 8 consecutive ci are
// contiguous in h. B direct from srwT (bf16 transposed, L2-hot).
__global__ __launch_bounds__(256) void k_srgemm(
    const bf16* __restrict__ h, const bf16* __restrict__ srwT,
    float* __restrict__ part) {
  const int tid = threadIdx.x, lane = tid & 63, wv = tid >> 6;
  const int quad = lane >> 4, li = lane & 15;
  const int rt = blockIdx.x >> 3, ks = blockIdx.x & 7;
  const int g = (rt << 6) + (wv << 4) + li;       // global patch row (A: m=li)
  const int b = g >> 8, pm = g & 255;
  const int py = pm >> 4, px = pm & 15;
  const int n0 = (py << 10) + (px << 3);          // patch origin token
  const size_t abase = ((size_t)(b * N_TOK + n0)) << 6;

  f4v acc[4];
#pragma unroll
  for (int t = 0; t < 4; t++) acc[t] = (f4v){0.f, 0.f, 0.f, 0.f};

#pragma unroll
  for (int i = 0; i < 16; i++) {
    const int kk = (ks << 4) + i;                 // k-step of 32
    const int sp = kk >> 1;                       // spatial tap 0..63
    const int nd = ((sp >> 3) << 7) + (sp & 7);   // token delta within patch
    const int ci = ((kk & 1) << 5) + (quad << 3);
    s8v av = *(const s8v*)(h + abase + (((size_t)nd) << 6) + ci);
    const int koff = (kk << 5) + (quad << 3);
#pragma unroll
    for (int t = 0; t < 4; t++) {
      s8v bv = *(const s8v*)(srwT + ((((t << 4) + li)) << 12) + koff);
      acc[t] = __builtin_amdgcn_mfma_f32_16x16x32_bf16(av, bv, acc[t], 0, 0, 0);
    }
  }
  float* pp = part + (((size_t)ks) << 17);        // ks * 2048*64
#pragma unroll
  for (int t = 0; t < 4; t++)
#pragma unroll
    for (int r = 0; r < 4; r++) {
      const int row = (rt << 6) + (wv << 4) + (quad << 2) + r;  // C: row=quad*4+r
      pp[(row << 6) + (t << 4) + li] = acc[t][r];
    }
}

// ---------------- kernel 2b: reduce partials + srnLN + kv projection ----------------
// 512 blocks x 256 thr; wave = one reduced token.
__global__ __launch_bounds__(256) void k_kv(
    const float* __restrict__ part, const float* __restrict__ srb,
    const float* __restrict__ sng, const float* __restrict__ snb,
    const float* __restrict__ kvw, const float* __restrict__ kvb,
    bf16* __restrict__ kbuf, bf16* __restrict__ vbufT) {
  const int tid = threadIdx.x, co = tid & 63, wv = tid >> 6;
  const int tok = (blockIdx.x << 2) + wv;
  float acc = srb[co];
#pragma unroll
  for (int s = 0; s < 8; s++) acc += part[(((size_t)s) << 17) + (tok << 6) + co];
  const float mean = wred_sum(acc) * (1.f / 64.f);
  const float d = acc - mean;
  const float var = wred_sum(d * d) * (1.f / 64.f);
  const float xn = d * rsqrtf(var + EPS) * sng[co] + snb[co];
  float ka = kvb[co];
  float va = kvb[64 + co];
#pragma unroll
  for (int ci = 0; ci < 64; ci++) {
    const float xv = __shfl(xn, ci);
    ka += xv * kvw[ci * 128 + co];
    va += xv * kvw[ci * 128 + 64 + co];
  }
  const int b = tok >> 8, nr = tok & 255;
  kbuf[(tok << 6) + co] = f2b(ka);
  vbufT[((((size_t)b << 6) + co) << 8) + nr] = f2b(va);
}

// ---------------- kernel 3: MFMA attention ----------------
__global__ __launch_bounds__(256) void k_attn(
    const bf16* __restrict__ h, const float* __restrict__ x,
    const bf16* __restrict__ qwT, const float* __restrict__ qb,
    const bf16* __restrict__ kbuf, const bf16* __restrict__ vbufT,
    const bf16* __restrict__ pwT, const float* __restrict__ pb,
    bf16* __restrict__ x2) {
  __shared__ __align__(16) short lds[36864];
  const int tid = threadIdx.x, lane = tid & 63, wv = tid >> 6;
  const int quad = lane >> 4, li = lane & 15;
  const int b = blockIdx.x >> 8;
  const int rowbase = ((blockIdx.x & 255) << 6) + (wv << 4);

#pragma unroll
  for (int it = 0; it < 8; it++) {
    const int idx = (it << 8) + tid;
    {
      const int row = idx >> 3, c8 = idx & 7;
      uint4 d = *(const uint4*)(kbuf + (((size_t)(b * 256 + row)) << 6) + (c8 << 3));
      *(uint4*)&lds[(row << 6) + ((c8 ^ (row & 7)) << 3)] = d;
    }
    {
      const int row = idx >> 5, c8 = idx & 31;
      uint4 d = *(const uint4*)(vbufT + (((size_t)(b * 64 + row)) << 8) + (c8 << 3));
      *(uint4*)&lds[16384 + (row << 8) + ((c8 ^ (row & 7)) << 3)] = d;
    }
  }

  s8v qwf[2][4];
#pragma unroll
  for (int s = 0; s < 2; s++)
#pragma unroll
    for (int t = 0; t < 4; t++) {
      const int n = (t << 4) + li;
      qwf[s][t] = *(const s8v*)(qwT + (n << 6) + ((((s << 2) + quad) ^ (n & 7)) << 3));
    }

  const size_t hbase = (((size_t)(b * N_TOK + rowbase + li)) << 6) + (quad << 3);
  s8v ha[2];
  ha[0] = *(const s8v*)(h + hbase);
  ha[1] = *(const s8v*)(h + hbase + 32);

  f4v qacc[4];
#pragma unroll
  for (int t = 0; t < 4; t++) {
    const float bv = qb[(t << 4) + li];
    qacc[t] = (f4v){bv, bv, bv, bv};
  }
#pragma unroll
  for (int s = 0; s < 2; s++)
#pragma unroll
    for (int t = 0; t < 4; t++)
      qacc[t] = __builtin_amdgcn_mfma_f32_16x16x32_bf16(ha[s], qwf[s][t], qacc[t], 0, 0, 0);

  const int qoff = 32768 + (wv << 10);
#pragma unroll
  for (int t = 0; t < 4; t++)
#pragma unroll
    for (int r = 0; r < 4; r++) {
      const int m = (quad << 2) + r, c = (t << 4) + li;
      lds[qoff + (m << 6) + ((((c >> 3) ^ (m & 7)) << 3)) + (c & 7)] = bfbits(qacc[t][r] * 0.125f);
    }
  __syncthreads();

  s8v qa[2];
#pragma unroll
  for (int s = 0; s < 2; s++)
    qa[s] = *(const s8v*)&lds[qoff + (li << 6) + ((((s << 2) + quad) ^ (li & 7)) << 3)];

  f4v sv[16];
#pragma unroll
  for (int t = 0; t < 16; t++) sv[t] = (f4v){0.f, 0.f, 0.f, 0.f};
#pragma unroll
  for (int t = 0; t < 16; t++)
#pragma unroll
    for (int s = 0; s < 2; s++) {
      s8v kb = *(const s8v*)&lds[(((t << 4) + li) << 6) + ((((s << 2) + quad) ^ (li & 7)) << 3)];
      sv[t] = __builtin_amdgcn_mfma_f32_16x16x32_bf16(qa[s], kb, sv[t], 0, 0, 0);
    }

  float rl[4];
#pragma unroll
  for (int r = 0; r < 4; r++) {
    float mx = -1e30f;
#pragma unroll
    for (int t = 0; t < 16; t++) mx = fmaxf(mx, sv[t][r]);
#pragma unroll
    for (int o = 1; o <= 8; o <<= 1) mx = fmaxf(mx, __shfl_xor(mx, o));
    float sm = 0.f;
#pragma unroll
    for (int t = 0; t < 16; t++) {
      const float e = __expf(sv[t][r] - mx);
      sv[t][r] = e;
      sm += e;
    }
#pragma unroll
    for (int o = 1; o <= 8; o <<= 1) sm += __shfl_xor(sm, o);
    rl[r] = 1.0f / sm;
  }
  __syncthreads();

  const int poff = wv << 12;
#pragma unroll
  for (int t = 0; t < 16; t++)
#pragma unroll
    for (int r = 0; r < 4; r++) {
      const int m = (quad << 2) + r, c = (t << 4) + li;
      lds[poff + (m << 8) + (((c >> 3) ^ (m & 7)) << 3) + (c & 7)] = bfbits(sv[t][r]);
    }

  f4v oacc[4];
#pragma unroll
  for (int t = 0; t < 4; t++) oacc[t] = (f4v){0.f, 0.f, 0.f, 0.f};
#pragma unroll
  for (int s = 0; s < 8; s++) {
    s8v pa = *(const s8v*)&lds[poff + (li << 8) + ((((s << 2) + quad) ^ (li & 7)) << 3)];
#pragma unroll
    for (int t = 0; t < 4; t++) {
      s8v vb = *(const s8v*)&lds[16384 + (((t << 4) + li) << 8) + ((((s << 2) + quad) ^ (li & 7)) << 3)];
      oacc[t] = __builtin_amdgcn_mfma_f32_16x16x32_bf16(pa, vb, oacc[t], 0, 0, 0);
    }
  }

#pragma unroll
  for (int t = 0; t < 4; t++)
#pragma unroll
    for (int r = 0; r < 4; r++) {
      const int m = (quad << 2) + r, c = (t << 4) + li;
      lds[qoff + (m << 6) + (((c >> 3) ^ (m & 7)) << 3) + (c & 7)] = bfbits(oacc[t][r] * rl[r]);
    }
  s8v oa[2];
#pragma unroll
  for (int s = 0; s < 2; s++)
    oa[s] = *(const s8v*)&lds[qoff + (li << 6) + ((((s << 2) + quad) ^ (li & 7)) << 3)];

  f4v pacc[4];
#pragma unroll
  for (int t = 0; t < 4; t++) {
    const float bv = pb[(t << 4) + li];
    pacc[t] = (f4v){bv, bv, bv, bv};
  }
#pragma unroll
  for (int s = 0; s < 2; s++)
#pragma unroll
    for (int t = 0; t < 4; t++) {
      const int n = (t << 4) + li;
      s8v wf = *(const s8v*)(pwT + (n << 6) + ((((s << 2) + quad) ^ (n & 7)) << 3));
      pacc[t] = __builtin_amdgcn_mfma_f32_16x16x32_bf16(oa[s], wf, pacc[t], 0, 0, 0);
    }
#pragma unroll
  for (int t = 0; t < 4; t++)
#pragma unroll
    for (int r = 0; r < 4; r++) {
      const size_t gi = (((size_t)(b * N_TOK + rowbase + (quad << 2) + r)) << 6) + (t << 4) + li;
      x2[gi] = f2b(x[gi] + pacc[t][r]);
    }
}

// ---------------- kernel 4: LN2 + fc1 (MFMA) ----------------
__global__ __launch_bounds__(256) void k_fc1(
    const bf16* __restrict__ x2, const float* __restrict__ g, const float* __restrict__ bb,
    const bf16* __restrict__ w1T, const float* __restrict__ b1,
    bf16* __restrict__ f) {
  __shared__ __align__(16) short hs[4096];
  const int tid = threadIdx.x, lane = tid & 63, wv = tid >> 6;
  const int quad = lane >> 4, li = lane & 15;
  const int r0 = blockIdx.x << 6;

  s8v wf[2][4];
  float bv[4];
#pragma unroll
  for (int t = 0; t < 4; t++) {
    const int n = (((wv << 2) + t) << 4) + li;
    bv[t] = b1[n];
#pragma unroll
    for (int s = 0; s < 2; s++)
      wf[s][t] = *(const s8v*)(w1T + (n << 6) + ((((s << 2) + quad) ^ (n & 7)) << 3));
  }

  const int row = tid >> 2, q4 = tid & 3;
  const bf16* xp = x2 + (((size_t)(r0 + row)) << 6) + (q4 << 4);
  s8v xa = *(const s8v*)xp;
  s8v xb = *(const s8v*)(xp + 8);
  float v[16];
#pragma unroll
  for (int j = 0; j < 8; j++) {
    v[j] = bits2f(xa[j]);
    v[8 + j] = bits2f(xb[j]);
  }
  float s = 0.f;
#pragma unroll
  for (int j = 0; j < 16; j++) s += v[j];
  s += __shfl_xor(s, 1); s += __shfl_xor(s, 2);
  const float mean = s * (1.f / 64.f);
  float vs = 0.f;
#pragma unroll
  for (int j = 0; j < 16; j++) { v[j] -= mean; vs += v[j] * v[j]; }
  vs += __shfl_xor(vs, 1); vs += __shfl_xor(vs, 2);
  const float rs = rsqrtf(vs * (1.f / 64.f) + EPS);
  s8v p0, p1;
#pragma unroll
  for (int j = 0; j < 16; j++) {
    const int c = (q4 << 4) + j;
    const short hb = bfbits(v[j] * rs * g[c] + bb[c]);
    if (j < 8) p0[j] = hb; else p1[j - 8] = hb;
  }
  {
    const int m7 = row & 7;
    *(s8v*)&hs[(row << 6) + (((q4 << 1) ^ m7) << 3)] = p0;
    *(s8v*)&hs[(row << 6) + ((((q4 << 1) + 1) ^ m7) << 3)] = p1;
  }
  __syncthreads();

  s8v qa[4][2];
#pragma unroll
  for (int rg = 0; rg < 4; rg++) {
    const int m = (rg << 4) + li;
#pragma unroll
    for (int s2 = 0; s2 < 2; s2++)
      qa[rg][s2] = *(const s8v*)&hs[(m << 6) + ((((s2 << 2) + quad) ^ (m & 7)) << 3)];
  }
  f4v acc[4][4];
#pragma unroll
  for (int rg = 0; rg < 4; rg++)
#pragma unroll
    for (int t = 0; t < 4; t++) acc[rg][t] = (f4v){bv[t], bv[t], bv[t], bv[t]};
#pragma unroll
  for (int rg = 0; rg < 4; rg++)
#pragma unroll
    for (int t = 0; t < 4; t++) {
      acc[rg][t] = __builtin_amdgcn_mfma_f32_16x16x32_bf16(qa[rg][0], wf[0][t], acc[rg][t], 0, 0, 0);
      acc[rg][t] = __builtin_amdgcn_mfma_f32_16x16x32_bf16(qa[rg][1], wf[1][t], acc[rg][t], 0, 0, 0);
    }
#pragma unroll
  for (int rg = 0; rg < 4; rg++)
#pragma unroll
    for (int t = 0; t < 4; t++)
#pragma unroll
      for (int r = 0; r < 4; r++) {
        const int rr = r0 + (rg << 4) + (quad << 2) + r;
        f[((size_t)rr << 8) + ((((wv << 2) + t) << 4)) + li] = f2b(acc[rg][t][r]);
      }
}

// ---------------- kernel 5: dw 3x3 + gelu + fc2 (MFMA) + residual ----------------
__global__ __launch_bounds__(256) void k_out(
    const bf16* __restrict__ f, const float* __restrict__ dww,
    const bf16* __restrict__ x2, const bf16* __restrict__ w2T,
    const float* __restrict__ fc2b, float* __restrict__ out) {
  __shared__ __align__(16) short gs[16384];
  __shared__ __align__(16) short w2s[16384];
  const int tid = threadIdx.x, lane = tid & 63, wv = tid >> 6;
  const int quad = lane >> 4, li = lane & 15;
  const int b = blockIdx.x >> 8;
  const int y = (blockIdx.x >> 1) & 127;
  const int xh = blockIdx.x & 1;

#pragma unroll
  for (int i = 0; i < 8; i++)
    ((uint4*)w2s)[(i << 8) + tid] = ((const uint4*)w2T)[(i << 8) + tid];

  const int tg = tid & 15, cg = tid >> 4;
  float acc[4][16];
#pragma unroll
  for (int t = 0; t < 4; t++)
#pragma unroll
    for (int j = 0; j < 16; j++) acc[t][j] = 0.f;

  const int x0 = (xh << 6) + (tg << 2);
  for (int dy = 0; dy < 3; dy++) {
    const int yy = y + dy - 1;
    if (yy < 0 || yy > 127) continue;
    float dwr[3][16];
#pragma unroll
    for (int dx = 0; dx < 3; dx++) {
      const float4* wp = (const float4*)(dww + (dy * 3 + dx) * HID + (cg << 4));
#pragma unroll
      for (int j4 = 0; j4 < 4; j4++) {
        const float4 w4 = wp[j4];
        dwr[dx][j4 * 4 + 0] = w4.x; dwr[dx][j4 * 4 + 1] = w4.y;
        dwr[dx][j4 * 4 + 2] = w4.z; dwr[dx][j4 * 4 + 3] = w4.w;
      }
    }
#pragma unroll
    for (int xi = -1; xi <= 4; xi++) {
      const int xx = x0 + xi;
      if (xx < 0 || xx > 127) continue;
      const bf16* fp = f + (((((size_t)(b * 128 + yy)) << 7) + xx) << 8) + (cg << 4);
      s8v fa = *(const s8v*)fp;
      s8v fb = *(const s8v*)(fp + 8);
      float fv[16];
#pragma unroll
      for (int j = 0; j < 8; j++) { fv[j] = bits2f(fa[j]); fv[8 + j] = bits2f(fb[j]); }
#pragma unroll
      for (int dx = 0; dx < 3; dx++) {
        const int t = xi - dx + 1;
        if (t < 0 || t > 3) continue;
#pragma unroll
        for (int j = 0; j < 16; j++) acc[t][j] += fv[j] * dwr[dx][j];
      }
    }
  }

#pragma unroll
  for (int t = 0; t < 4; t++) {
    const int m = (tg << 2) + t;
    s8v p0, p1;
#pragma unroll
    for (int j = 0; j < 16; j++) {
      const float a = acc[t][j];
      const float ge = 0.5f * a * (1.f + erff(a * 0.70710678118654752f));
      if (j < 8) p0[j] = bfbits(ge); else p1[j - 8] = bfbits(ge);
    }
    const int m7 = m & 7;
    *(s8v*)&gs[(m << 8) + (((cg << 1) ^ m7) << 3)] = p0;
    *(s8v*)&gs[(m << 8) + ((((cg << 1) + 1) ^ m7) << 3)] = p1;
  }
  __syncthreads();

  f4v oa2[4];
#pragma unroll
  for (int ct = 0; ct < 4; ct++) {
    const float bb2 = fc2b[(ct << 4) + li];
    oa2[ct] = (f4v){bb2, bb2, bb2, bb2};
  }
  const int m = (wv << 4) + li;
#pragma unroll
  for (int kc = 0; kc < 8; kc++) {
    const int ch = (kc << 2) + quad;
    s8v av = *(const s8v*)&gs[(m << 8) + ((ch ^ (m & 7)) << 3)];
#pragma unroll
    for (int ct = 0; ct < 4; ct++) {
      const int n = (ct << 4) + li;
      s8v bv2 = *(const s8v*)&w2s[(n << 8) + ((ch ^ (n & 7)) << 3)];
      oa2[ct] = __builtin_amdgcn_mfma_f32_16x16x32_bf16(av, bv2, oa2[ct], 0, 0, 0);
    }
  }
  const int tokbase = (b << 14) + (y << 7) + (xh << 6) + (wv << 4) + (quad << 2);
#pragma unroll
  for (int ct = 0; ct < 4; ct++)
#pragma unroll
    for (int r = 0; r < 4; r++) {
      const size_t gi = (((size_t)(tokbase + r)) << 6) + (ct << 4) + li;
      out[gi] = b2f(x2[gi]) + oa2[ct][r];
    }
}

extern "C" void kernel_launch(void* const* d_in, const int* in_sizes, int n_in,
                              void* d_out, int out_size, void* d_ws, size_t ws_size,
                              hipStream_t stream) {
  const float* x    = (const float*)d_in[0];
  const float* ln1g = (const float*)d_in[3];
  const float* ln1b = (const float*)d_in[4];
  const float* qw   = (const float*)d_in[5];
  const float* qb   = (const float*)d_in[6];
  const float* kvw  = (const float*)d_in[7];
  const float* kvb  = (const float*)d_in[8];
  const float* pw   = (const float*)d_in[9];
  const float* pb   = (const float*)d_in[10];
  const float* srw  = (const float*)d_in[11];
  const float* srb  = (const float*)d_in[12];
  const float* sng  = (const float*)d_in[13];
  const float* snb  = (const float*)d_in[14];
  const float* ln2g = (const float*)d_in[15];
  const float* ln2b = (const float*)d_in[16];
  const float* w1   = (const float*)d_in[17];
  const float* b1   = (const float*)d_in[18];
  const float* dww  = (const float*)d_in[19];
  const float* w2   = (const float*)d_in[20];
  const float* b2v  = (const float*)d_in[21];
  float* out = (float*)d_out;

  char* ws = (char*)d_ws;
  bf16*  x2    = (bf16*)ws;                    // 16,777,216 B
  bf16*  h     = (bf16*)(ws + 16777216);       // 16,777,216 B
  bf16*  kbuf  = (bf16*)(ws + 33554432);       //    262,144 B
  bf16*  vbufT = (bf16*)(ws + 33816576);       //    262,144 B
  bf16*  fbuf  = (bf16*)(ws + 34078720);       // 67,108,864 B
  bf16*  w1T   = (bf16*)(ws + 101187584);      //     32,768 B
  bf16*  w2T   = (bf16*)(ws + 101220352);      //     32,768 B
  bf16*  qwT   = (bf16*)(ws + 101253120);      //      8,192 B
  bf16*  pwT   = (bf16*)(ws + 101261312);      //      8,192 B
  bf16*  srwT  = (bf16*)(ws + 101269504);      //    524,288 B
  float* part  = (float*)(ws + 101793792);     //  4,194,304 B

  k_prep  <<< 1184, 256, 0, stream>>>(qw, pw, w1, w2, srw, qwT, pwT, w1T, w2T, srwT);
  k_ln1   <<< 2048, 256, 0, stream>>>(x, ln1g, ln1b, h);
  k_srgemm<<<  256, 256, 0, stream>>>(h, srwT, part);
  k_kv    <<<  512, 256, 0, stream>>>(part, srb, sng, snb, kvw, kvb, kbuf, vbufT);
  k_attn  <<< 2048, 256, 0, stream>>>(h, x, qwT, qb, kbuf, vbufT, pwT, pb, x2);
  k_fc1   <<< 2048, 256, 0, stream>>>(x2, ln2g, ln2b, w1T, b1, fbuf);
  k_out   <<< 2048, 256, 0, stream>>>(fbuf, dww, x2, w2T, b2v, out);
}